// Round 9
// baseline (203.060 us; speedup 1.0000x reference)
//
#include <hip/hip_runtime.h>
#include <math.h>

// MultiHeadAttention: B=2,S=2048,E=1024,H=16,DH=64,A=1024. fp32 in/out.
// Round 9: GEMMs get the R7/R8 pipeline: VGPR prefetch of next K-tile during
// compute + ds_write staging between raw lds_barriers (no vmcnt drain at the
// barrier -- the m97 global_load_lds+__syncthreads structure drains ~20%).
// Attention unchanged from R8 (QT=128 + prefetch, 62 us). W-casts merged.
// d_ws (bf16 elems): xb[4Mi] qb[4Mi] kb[4Mi] vtb[4Mi] cc[4Mi] Wt[3Mi] Wot[1Mi]

namespace {
constexpr int kBn = 2, kS = 2048, kE = 1024, kH = 16, kDH = 64, kA = 1024;

typedef __attribute__((ext_vector_type(8))) short short8;
typedef __attribute__((ext_vector_type(4))) float f32x4;

// q pre-scale: (1/sqrt(DH)) * log2(e) so attention uses raw v_exp_f32.
#define QSCALE 0.18033688011112042f

__device__ inline unsigned short f2bf(float f) {
  union { float f; unsigned u; } x; x.f = f;
  unsigned r = x.u + 0x7fffu + ((x.u >> 16) & 1u);   // RNE
  return (unsigned short)(r >> 16);
}

// Raw workgroup barrier: LDS ordering only (lgkmcnt), no vmcnt drain.
__device__ inline void lds_barrier() {
  asm volatile("s_waitcnt lgkmcnt(0)" ::: "memory");
  __builtin_amdgcn_s_barrier();
}

// ---------------- cast x: fp32 -> bf16, elementwise ----------------------
__global__ __launch_bounds__(256) void cast_x_kernel(
    const float* __restrict__ x, unsigned short* __restrict__ xb) {
  const int i = (blockIdx.x * 256 + threadIdx.x) * 8;
  float4 a = *(const float4*)(x + i);
  float4 b = *(const float4*)(x + i + 4);
  unsigned short t[8];
  t[0] = f2bf(a.x); t[1] = f2bf(a.y); t[2] = f2bf(a.z); t[3] = f2bf(a.w);
  t[4] = f2bf(b.x); t[5] = f2bf(b.y); t[6] = f2bf(b.z); t[7] = f2bf(b.w);
  *(short8*)(xb + i) = *(const short8*)t;
}

// ---- cast+transpose weights: z<3 -> Wq/Wk/Wv [H,E,DH]->[sel][h*64+d][e];
//      z==3 -> Wo [A,E]->[e][a] ------------------------------------------
__global__ __launch_bounds__(256) void cast_w_kernel(
    const float* __restrict__ Wq, const float* __restrict__ Wk,
    const float* __restrict__ Wv, const float* __restrict__ Wo,
    unsigned short* __restrict__ Wt, unsigned short* __restrict__ Wot) {
  const int sel = blockIdx.z;
  const int tid = threadIdx.x;
  __shared__ float T[64][68];

  if (sel < 3) {
    const float* __restrict__ W = (sel == 0) ? Wq : (sel == 1) ? Wk : Wv;
    const int h = blockIdx.y;
    const int e0 = blockIdx.x * 64;
    const int el = tid >> 2, dq = tid & 3;
    const float* src = W + ((size_t)h * kE + e0 + el) * kDH + dq * 16;
#pragma unroll
    for (int j = 0; j < 4; ++j)
      *(float4*)&T[el][dq * 16 + j * 4] = *(const float4*)(src + j * 4);
    __syncthreads();

    const int d = tid & 63, w = tid >> 6;
    unsigned short t[16];
#pragma unroll
    for (int j = 0; j < 16; ++j) t[j] = f2bf(T[w * 16 + j][d]);
    unsigned short* dst =
        Wt + (((size_t)sel << 20) | ((size_t)(h * 64 + d) << 10)) + e0 + w * 16;
    *(short8*)dst = *(const short8*)&t[0];
    *(short8*)(dst + 8) = *(const short8*)&t[8];
  } else {
    const int a0 = blockIdx.x * 64, e0 = blockIdx.y * 64;
    const int al = tid >> 2, dq = tid & 3;
    const float* src = Wo + (size_t)(a0 + al) * kE + e0 + dq * 16;
#pragma unroll
    for (int j = 0; j < 4; ++j)
      *(float4*)&T[al][dq * 16 + j * 4] = *(const float4*)(src + j * 4);
    __syncthreads();

    const int e = tid & 63, w = tid >> 6;
    unsigned short t[16];
#pragma unroll
    for (int j = 0; j < 16; ++j) t[j] = f2bf(T[w * 16 + j][e]);
    unsigned short* dst = Wot + ((size_t)(e0 + e) << 10) + a0 + w * 16;
    *(short8*)dst = *(const short8*)&t[0];
    *(short8*)(dst + 8) = *(const short8*)&t[8];
  }
}

// ---------------- QKV GEMM, pipelined (modes 0/1/2 over blockIdx.z) ------
// mode 0: q -> [B,H,S,DH] bf16, scaled by QSCALE. mode 1: k -> same, no scale.
// mode 2: v -> [B,H,DH,S] bf16.  VGPR prefetch + raw barriers.
__global__ __launch_bounds__(256) void gemm_bf16_kernel(
    const unsigned short* __restrict__ A, const unsigned short* __restrict__ Bt,
    const float* __restrict__ b0, const float* __restrict__ b1,
    const float* __restrict__ b2,
    unsigned short* __restrict__ oq, unsigned short* __restrict__ okk,
    unsigned short* __restrict__ ov) {
  constexpr int K = 1024;
  const int mode = (int)blockIdx.z;
  const unsigned short* Bm = Bt + ((size_t)blockIdx.z << 20);
  const float* bias = (mode == 1) ? b1 : (mode == 2) ? b2 : b0;

  const int mt = blockIdx.x, nt = blockIdx.y;
  const int tid = threadIdx.x;
  const int wv = tid >> 6, lane = tid & 63, lq = lane & 15, quad = lane >> 4;
  const int wm = wv >> 1, wn = wv & 1;

  __shared__ unsigned short lA[128 * 32];
  __shared__ unsigned short lB[128 * 32];

  // chunk c (0..511): row = c>>2, kcol = (c&3)*8; chunk c lives at lds+c*8
  const int c0 = wv * 64 + lane;
  const int c1 = c0 + 256;
  const unsigned short* gA0 = A + (size_t)(mt * 128 + (c0 >> 2)) * K + (c0 & 3) * 8;
  const unsigned short* gA1 = A + (size_t)(mt * 128 + (c1 >> 2)) * K + (c1 & 3) * 8;
  const unsigned short* gB0 = Bm + (size_t)(nt * 128 + (c0 >> 2)) * K + (c0 & 3) * 8;
  const unsigned short* gB1 = Bm + (size_t)(nt * 128 + (c1 >> 2)) * K + (c1 & 3) * 8;
  unsigned short* dA0 = lA + (size_t)c0 * 8;
  unsigned short* dA1 = lA + (size_t)c1 * 8;
  unsigned short* dB0 = lB + (size_t)c0 * 8;
  unsigned short* dB1 = lB + (size_t)c1 * 8;

  f32x4 acc[4][4];
#pragma unroll
  for (int i = 0; i < 4; ++i)
#pragma unroll
    for (int j = 0; j < 4; ++j) acc[i][j] = (f32x4){0.f, 0.f, 0.f, 0.f};

  // prologue: prefetch K-tile 0
  short8 rA0 = *(const short8*)gA0;
  short8 rA1 = *(const short8*)gA1;
  short8 rB0 = *(const short8*)gB0;
  short8 rB1 = *(const short8*)gB1;

  for (int k0 = 0; k0 < K; k0 += 32) {
    lds_barrier();                 // all waves done reading prev tile
    *(short8*)dA0 = rA0;           // waits vmcnt only for rA/rB
    *(short8*)dA1 = rA1;
    *(short8*)dB0 = rB0;
    *(short8*)dB1 = rB1;
    if (k0 + 32 < K) {             // prefetch next tile; stays in flight
      rA0 = *(const short8*)(gA0 + k0 + 32);
      rA1 = *(const short8*)(gA1 + k0 + 32);
      rB0 = *(const short8*)(gB0 + k0 + 32);
      rB1 = *(const short8*)(gB1 + k0 + 32);
    }
    lds_barrier();                 // tile visible to all waves

    short8 af[4], bfr[4];
#pragma unroll
    for (int i = 0; i < 4; ++i)
      af[i] = *(const short8*)&lA[(wm * 64 + i * 16 + lq) * 32 + quad * 8];
#pragma unroll
    for (int j = 0; j < 4; ++j)
      bfr[j] = *(const short8*)&lB[(wn * 64 + j * 16 + lq) * 32 + quad * 8];
#pragma unroll
    for (int i = 0; i < 4; ++i)
#pragma unroll
      for (int j = 0; j < 4; ++j)
        acc[i][j] = __builtin_amdgcn_mfma_f32_16x16x32_bf16(af[i], bfr[j],
                                                            acc[i][j], 0, 0, 0);
  }

  const int n0 = nt * 128 + wn * 64;
  float bv4[4];
#pragma unroll
  for (int j = 0; j < 4; ++j) bv4[j] = bias[n0 + j * 16 + lq];

  const int tok0 = mt * 128 + wm * 64;
  const int b = tok0 >> 11;
  const int s0 = tok0 & (kS - 1);
  const int h = n0 >> 6;
  if (mode < 2) {
    unsigned short* o = (mode == 0) ? oq : okk;
    const float scl = (mode == 0) ? QSCALE : 1.0f;
#pragma unroll
    for (int i = 0; i < 4; ++i)
#pragma unroll
      for (int j = 0; j < 4; ++j) {
        const int d = j * 16 + lq;
#pragma unroll
        for (int r = 0; r < 4; ++r) {
          const int s = s0 + i * 16 + quad * 4 + r;
          o[((size_t)(b * kH + h) * kS + s) * kDH + d] =
              f2bf((acc[i][j][r] + bv4[j]) * scl);
        }
      }
  } else {
#pragma unroll
    for (int i = 0; i < 4; ++i)
#pragma unroll
      for (int j = 0; j < 4; ++j) {
        const int d = j * 16 + lq;
        union { unsigned short u[4]; uint2 v; } pk;
#pragma unroll
        for (int r = 0; r < 4; ++r) pk.u[r] = f2bf(acc[i][j][r] + bv4[j]);
        const int s = s0 + i * 16 + quad * 4;
        *(uint2*)(ov + ((size_t)(b * kH + h) * kDH + d) * kS + s) = pk.v;
      }
  }
}

// ---------------- out-proj GEMM, pipelined: 128x64 tiles, fp32 out -------
__global__ __launch_bounds__(256) void gemm_out_kernel(
    const unsigned short* __restrict__ A, const unsigned short* __restrict__ Bt,
    const float* __restrict__ bo, float* __restrict__ of) {
  constexpr int K = 1024;
  const int mt = blockIdx.x, nt = blockIdx.y;
  const int tid = threadIdx.x;
  const int wv = tid >> 6, lane = tid & 63, lq = lane & 15, quad = lane >> 4;
  const int wm = wv >> 1, wn = wv & 1;

  __shared__ unsigned short lA[128 * 32];   // 8 KB
  __shared__ unsigned short lB[64 * 32];    // 4 KB

  const int c0 = wv * 64 + lane;
  const int c1 = c0 + 256;
  const unsigned short* gA0 = A + (size_t)(mt * 128 + (c0 >> 2)) * K + (c0 & 3) * 8;
  const unsigned short* gA1 = A + (size_t)(mt * 128 + (c1 >> 2)) * K + (c1 & 3) * 8;
  const unsigned short* gB0 = Bt + (size_t)(nt * 64 + (c0 >> 2)) * K + (c0 & 3) * 8;
  unsigned short* dA0 = lA + (size_t)c0 * 8;
  unsigned short* dA1 = lA + (size_t)c1 * 8;
  unsigned short* dB0 = lB + (size_t)c0 * 8;

  f32x4 acc[4][2];
#pragma unroll
  for (int i = 0; i < 4; ++i)
#pragma unroll
    for (int j = 0; j < 2; ++j) acc[i][j] = (f32x4){0.f, 0.f, 0.f, 0.f};

  short8 rA0 = *(const short8*)gA0;
  short8 rA1 = *(const short8*)gA1;
  short8 rB0 = *(const short8*)gB0;

  for (int k0 = 0; k0 < K; k0 += 32) {
    lds_barrier();
    *(short8*)dA0 = rA0;
    *(short8*)dA1 = rA1;
    *(short8*)dB0 = rB0;
    if (k0 + 32 < K) {
      rA0 = *(const short8*)(gA0 + k0 + 32);
      rA1 = *(const short8*)(gA1 + k0 + 32);
      rB0 = *(const short8*)(gB0 + k0 + 32);
    }
    lds_barrier();

    short8 af[4], bfr[2];
#pragma unroll
    for (int i = 0; i < 4; ++i)
      af[i] = *(const short8*)&lA[(wm * 64 + i * 16 + lq) * 32 + quad * 8];
#pragma unroll
    for (int j = 0; j < 2; ++j)
      bfr[j] = *(const short8*)&lB[(wn * 32 + j * 16 + lq) * 32 + quad * 8];
#pragma unroll
    for (int i = 0; i < 4; ++i)
#pragma unroll
      for (int j = 0; j < 2; ++j)
        acc[i][j] = __builtin_amdgcn_mfma_f32_16x16x32_bf16(af[i], bfr[j],
                                                            acc[i][j], 0, 0, 0);
  }

  const int n0 = nt * 64 + wn * 32;
  const int m0 = mt * 128 + wm * 64;
  float bv2[2];
#pragma unroll
  for (int j = 0; j < 2; ++j) bv2[j] = bo[n0 + j * 16 + lq];
#pragma unroll
  for (int i = 0; i < 4; ++i)
#pragma unroll
    for (int j = 0; j < 2; ++j)
#pragma unroll
      for (int r = 0; r < 4; ++r)
        of[(size_t)(m0 + i * 16 + quad * 4 + r) * kE + n0 + j * 16 + lq] =
            acc[i][j][r] + bv2[j];
}

// ---------------- bf16 MFMA flash attention, QT=128 + prefetch -----------
// (unchanged from R8: 62 us, MfmaUtil 24%)
#define QT 128
#define KT 64
#define LDK 72
__global__ __launch_bounds__(256) void attn_mfma_kernel(
    const unsigned short* __restrict__ q, const unsigned short* __restrict__ k,
    const unsigned short* __restrict__ vt, unsigned short* __restrict__ cc) {
  const int bh = blockIdx.y;
  const int b = bh >> 4, h = bh & 15;
  const int tid = threadIdx.x;
  const int wv = tid >> 6;
  const int lane = tid & 63;
  const int lq = lane & 15;
  const int quad = lane >> 4;

  __shared__ unsigned short Ks[KT][LDK];   // [t][d]   9 KB
  __shared__ unsigned short Vt[kDH][LDK];  // [d][t]   9 KB
  __shared__ unsigned short Pb[QT][LDK];   // [q][t]  18 KB, wave-private rows

  const int q0 = blockIdx.x * QT;

  short8 qa[2][2];
#pragma unroll
  for (int mf = 0; mf < 2; ++mf) {
    const unsigned short* qbase =
        q + ((size_t)bh * kS + q0 + wv * 32 + mf * 16 + lq) * kDH;
    qa[mf][0] = *(const short8*)(qbase + quad * 8);
    qa[mf][1] = *(const short8*)(qbase + 32 + quad * 8);
  }

  f32x4 Oacc[2][4];
  f32x4 Osum[2];
#pragma unroll
  for (int mf = 0; mf < 2; ++mf) {
    Osum[mf] = (f32x4){0.f, 0.f, 0.f, 0.f};
#pragma unroll
    for (int dt = 0; dt < 4; ++dt) Oacc[mf][dt] = (f32x4){0.f, 0.f, 0.f, 0.f};
  }

  unsigned short ob[8];
#pragma unroll
  for (int i = 0; i < 8; ++i) ob[i] = 0x3F80;   // bf16 1.0
  const short8 ones = *(const short8*)ob;

  const unsigned short* kg = k + (size_t)bh * kS * kDH;
  const unsigned short* vg = vt + (size_t)bh * kDH * kS;

  const int sr = tid >> 3;
  const int sc = (tid & 7) << 3;

  short8 rk0 = *(const short8*)(kg + (size_t)sr * kDH + sc);
  short8 rk1 = *(const short8*)(kg + (size_t)(sr + 32) * kDH + sc);
  short8 rv0 = *(const short8*)(vg + (size_t)sr * kS + sc);
  short8 rv1 = *(const short8*)(vg + (size_t)(sr + 32) * kS + sc);

  for (int t0 = 0; t0 < kS; t0 += KT) {
    lds_barrier();
    *(short8*)&Ks[sr][sc]       = rk0;
    *(short8*)&Ks[sr + 32][sc]  = rk1;
    *(short8*)&Vt[sr][sc]       = rv0;
    *(short8*)&Vt[sr + 32][sc]  = rv1;
    if (t0 + KT < kS) {
      const int tn = t0 + KT;
      rk0 = *(const short8*)(kg + (size_t)(tn + sr) * kDH + sc);
      rk1 = *(const short8*)(kg + (size_t)(tn + sr + 32) * kDH + sc);
      rv0 = *(const short8*)(vg + (size_t)sr * kS + tn + sc);
      rv1 = *(const short8*)(vg + (size_t)(sr + 32) * kS + tn + sc);
    }
    lds_barrier();

    f32x4 S[2][4];
#pragma unroll
    for (int nt = 0; nt < 4; ++nt) {
      short8 kb0 = *(const short8*)&Ks[nt * 16 + lq][quad * 8];
      short8 kb1 = *(const short8*)&Ks[nt * 16 + lq][32 + quad * 8];
#pragma unroll
      for (int mf = 0; mf < 2; ++mf) {
        f32x4 acc = (f32x4){0.f, 0.f, 0.f, 0.f};
        acc = __builtin_amdgcn_mfma_f32_16x16x32_bf16(qa[mf][0], kb0, acc, 0, 0, 0);
        acc = __builtin_amdgcn_mfma_f32_16x16x32_bf16(qa[mf][1], kb1, acc, 0, 0, 0);
        S[mf][nt] = acc;
      }
    }

#pragma unroll
    for (int mf = 0; mf < 2; ++mf)
#pragma unroll
      for (int nt = 0; nt < 4; ++nt)
#pragma unroll
        for (int r = 0; r < 4; ++r) {
          const float p = __builtin_amdgcn_exp2f(S[mf][nt][r]);
          union { float f; unsigned u; } x; x.f = p;
          Pb[wv * 32 + mf * 16 + quad * 4 + r][nt * 16 + lq] =
              (unsigned short)((x.u + 0x8000u) >> 16);
        }

    short8 pa[2][2];
#pragma unroll
    for (int mf = 0; mf < 2; ++mf) {
      pa[mf][0] = *(const short8*)&Pb[wv * 32 + mf * 16 + lq][quad * 8];
      pa[mf][1] = *(const short8*)&Pb[wv * 32 + mf * 16 + lq][32 + quad * 8];
    }

#pragma unroll
    for (int dt = 0; dt < 4; ++dt) {
      short8 vb0 = *(const short8*)&Vt[dt * 16 + lq][quad * 8];
      short8 vb1 = *(const short8*)&Vt[dt * 16 + lq][32 + quad * 8];
#pragma unroll
      for (int mf = 0; mf < 2; ++mf) {
        Oacc[mf][dt] =
            __builtin_amdgcn_mfma_f32_16x16x32_bf16(pa[mf][0], vb0, Oacc[mf][dt], 0, 0, 0);
        Oacc[mf][dt] =
            __builtin_amdgcn_mfma_f32_16x16x32_bf16(pa[mf][1], vb1, Oacc[mf][dt], 0, 0, 0);
      }
    }
#pragma unroll
    for (int mf = 0; mf < 2; ++mf) {
      Osum[mf] = __builtin_amdgcn_mfma_f32_16x16x32_bf16(pa[mf][0], ones, Osum[mf], 0, 0, 0);
      Osum[mf] = __builtin_amdgcn_mfma_f32_16x16x32_bf16(pa[mf][1], ones, Osum[mf], 0, 0, 0);
    }
  }

#pragma unroll
  for (int mf = 0; mf < 2; ++mf)
#pragma unroll
    for (int r = 0; r < 4; ++r) {
      const float inv = 1.0f / Osum[mf][r];
      const int qrow = q0 + wv * 32 + mf * 16 + quad * 4 + r;
      unsigned short* base = cc + ((size_t)b * kS + qrow) * kA + h * kDH;
#pragma unroll
      for (int dt = 0; dt < 4; ++dt)
        base[dt * 16 + lq] = f2bf(Oacc[mf][dt][r] * inv);
    }
}

}  // namespace

extern "C" void kernel_launch(void* const* d_in, const int* in_sizes, int n_in,
                              void* d_out, int out_size, void* d_ws, size_t ws_size,
                              hipStream_t stream) {
  const float* x  = (const float*)d_in[0];
  const float* Wq = (const float*)d_in[1];
  const float* bq = (const float*)d_in[2];
  const float* Wk = (const float*)d_in[3];
  const float* bk = (const float*)d_in[4];
  const float* Wv = (const float*)d_in[5];
  const float* bv = (const float*)d_in[6];
  const float* Wo = (const float*)d_in[7];
  const float* bo = (const float*)d_in[8];
  float* out = (float*)d_out;

  const size_t per = (size_t)kBn * kH * kS * kDH;  // 4 Mi elems
  unsigned short* xb  = (unsigned short*)d_ws;
  unsigned short* qb  = xb + per;
  unsigned short* kb  = qb + per;
  unsigned short* vtb = kb + per;
  unsigned short* cc  = vtb + per;
  unsigned short* Wt  = cc + per;          // 3 Mi
  unsigned short* Wot = Wt + 3 * (per / 4);

  cast_x_kernel<<<dim3(per / (256 * 8)), 256, 0, stream>>>(x, xb);
  cast_w_kernel<<<dim3(16, 16, 4), 256, 0, stream>>>(Wq, Wk, Wv, Wo, Wt, Wot);

  gemm_bf16_kernel<<<dim3(32, 8, 3), 256, 0, stream>>>(
      xb, Wt, bq, bk, bv, qb, kb, vtb);

  attn_mfma_kernel<<<dim3(kS / QT, kBn * kH), 256, 0, stream>>>(qb, kb, vtb, cc);

  gemm_out_kernel<<<dim3(32, 16), 256, 0, stream>>>(cc, Wot, bo, out);
}